// Round 2
// baseline (5838.800 us; speedup 1.0000x reference)
//
#include <hip/hip_runtime.h>
#include <hip/hip_bf16.h>
#include <math.h>

typedef __hip_bfloat16 bf16;

#define NNODES 50000
#define NHALF  25000
#define NEDGES 400000
#define NEG_SLOPE 0.2f

__device__ __forceinline__ float b2f(bf16 x){ return __bfloat162float(x); }
__device__ __forceinline__ bf16  f2b(float x){ return __float2bfloat16(x); }

// order-preserving float<->uint mapping for atomicMax on floats
__device__ __forceinline__ unsigned fmap(float x){
  unsigned u = __float_as_uint(x);
  return (u & 0x80000000u) ? ~u : (u | 0x80000000u);
}
__device__ __forceinline__ float funmap(unsigned u){
  unsigned b = (u & 0x80000000u) ? (u & 0x7FFFFFFFu) : ~u;
  return __uint_as_float(b);
}

// flag-dependent loads/stores (flags[0]=1 -> tensors are fp32; 0 -> bf16)
__device__ __forceinline__ float loadF(const void* p, long i, int f32){
  return f32 ? ((const float*)p)[i] : b2f(((const bf16*)p)[i]);
}
__device__ __forceinline__ void storeOut(void* p, long i, float v, int f32){
  if (f32) ((float*)p)[i] = v; else ((bf16*)p)[i] = f2b(v);
}

// ---------------- dtype / index-width detection ------------------------------
// flags[0]: 1 if float tensors are fp32, 0 if bf16
// flags[1]: 1 if index tensors are int64, 0 if int32
__global__ void k_detect(const unsigned short* __restrict__ x0u,
                         const unsigned* __restrict__ dstu,
                         int* __restrict__ flags)
{
  __shared__ int sh_insane;
  __shared__ unsigned sh_or;
  if (threadIdx.x == 0) { sh_insane = 0; sh_or = 0u; }
  __syncthreads();
  int insane = 0; unsigned orv = 0u;
  for (int i = threadIdx.x; i < 2048; i += 256) {
    unsigned short w = x0u[2 * i];            // even 16-bit words of x0
    int ex = (w >> 7) & 0xFF;
    if (w != 0 && (ex < 108 || ex > 142)) insane++;
    orv |= dstu[2 * i + 1];                    // odd 32-bit words of dst
  }
  atomicAdd(&sh_insane, insane);
  atomicOr(&sh_or, orv);
  __syncthreads();
  if (threadIdx.x == 0) {
    flags[0] = (sh_insane > 512) ? 1 : 0;      // fp32 low-halves look insane
    flags[1] = (sh_or == 0u) ? 1 : 0;          // int64 high words are all zero
  }
}

// ---------------- index conversion to int32 ----------------------------------
__global__ void k_conv_idx(const int* __restrict__ sraw, const int* __restrict__ draw,
                           int* __restrict__ s32, int* __restrict__ d32,
                           const int* __restrict__ flags)
{
  int e = blockIdx.x * blockDim.x + threadIdx.x;
  if (e >= NEDGES) return;
  int stride = flags[1] ? 2 : 1;               // int64 little-endian: take low word
  s32[e] = sraw[(long)e * stride];
  d32[e] = draw[(long)e * stride];
}

// ---------------- weight canonicalization to bf16 ----------------------------
struct WSrc { const void* p[17]; int n[17]; };

__global__ void k_canon(WSrc w, bf16* __restrict__ out, const int* __restrict__ flags,
                        int total)
{
  int f32 = flags[0];
  for (int t = blockIdx.x * blockDim.x + threadIdx.x; t < total;
       t += gridDim.x * blockDim.x) {
    int idx = t, k = 0;
    while (idx >= w.n[k]) { idx -= w.n[k]; k++; }
    out[t] = f2b(loadF(w.p[k], idx, f32));
  }
}

// ---------------- input projection: h0[n,64] = x_t[n] @ fcW_t + fcb_t --------
__global__ void k_fc(const void* __restrict__ x0, const void* __restrict__ x1,
                     const bf16* __restrict__ w0, const bf16* __restrict__ b0,
                     const bf16* __restrict__ w1, const bf16* __restrict__ b1,
                     bf16* __restrict__ out, const int* __restrict__ flags)
{
  int t = blockIdx.x * blockDim.x + threadIdx.x;
  if (t >= NNODES * 64) return;
  int f32 = flags[0];
  int n = t >> 6, c = t & 63;
  const void* x; long base; const bf16* W; const bf16* B;
  if (n < NHALF) { x = x0; base = (long)n * 256;           W = w0; B = b0; }
  else           { x = x1; base = (long)(n - NHALF) * 256; W = w1; B = b1; }
  float acc = b2f(B[c]);
  for (int k = 0; k < 256; ++k)
    acc += loadF(x, base + k, f32) * b2f(W[(long)k * 64 + c]);
  out[t] = f2b(acc);
}

// ---------------- naive GEMM: out[N,M] = A[N,K] @ W[K,M] (bf16 in/out) -------
__global__ void k_gemm(const bf16* __restrict__ A, const bf16* __restrict__ W,
                       bf16* __restrict__ out, int N, int K, int M)
{
  long t = (long)blockIdx.x * blockDim.x + threadIdx.x;
  if (t >= (long)N * M) return;
  int r = (int)(t / M), c = (int)(t % M);
  const bf16* a = A + (long)r * K;
  float acc = 0.f;
  for (int k = 0; k < K; ++k)
    acc += b2f(a[k]) * b2f(W[(long)k * M + c]);
  out[t] = f2b(acc);
}

// ---------------- attention logits per node ----------------------------------
__global__ void k_elr(const bf16* __restrict__ ft,
                      const bf16* __restrict__ al, const bf16* __restrict__ ar,
                      float* __restrict__ el, float* __restrict__ er,
                      int N, int H, int D)
{
  int t = blockIdx.x * blockDim.x + threadIdx.x;
  if (t >= N * H) return;
  int n = t / H, h = t % H;
  const bf16* f = ft + (long)n * H * D + (long)h * D;
  float a = 0.f, b = 0.f;
  for (int d = 0; d < D; ++d) {
    float v = b2f(f[d]);
    a += v * b2f(al[h * D + d]);
    b += v * b2f(ar[h * D + d]);
  }
  el[t] = a; er[t] = b;
}

// ---------------- edge pass A: leaky_relu + segment max ----------------------
__global__ void k_edge_a(const int* __restrict__ src, const int* __restrict__ dst,
                         const float* __restrict__ el, const float* __restrict__ er,
                         float* __restrict__ eval, unsigned* __restrict__ m,
                         int E, int H)
{
  int t = blockIdx.x * blockDim.x + threadIdx.x;
  if (t >= E * H) return;
  int e = t / H, h = t % H;
  float v = el[src[e] * H + h] + er[dst[e] * H + h];
  v = v > 0.f ? v : NEG_SLOPE * v;
  eval[t] = v;
  atomicMax(&m[dst[e] * H + h], fmap(v));
}

// ---------------- edge pass B: exp(e - m[dst]) + segment sum -----------------
__global__ void k_edge_b(const int* __restrict__ dst,
                         float* __restrict__ eval, const unsigned* __restrict__ m,
                         float* __restrict__ s, int E, int H)
{
  int t = blockIdx.x * blockDim.x + threadIdx.x;
  if (t >= E * H) return;
  int e = t / H, h = t % H;
  float mm = funmap(m[dst[e] * H + h]);
  float ex = expf(eval[t] - mm);
  eval[t] = ex;
  atomicAdd(&s[dst[e] * H + h], ex);
}

// ---------------- CSR build --------------------------------------------------
__global__ void k_deg(const int* __restrict__ dst, int* __restrict__ deg, int E)
{
  int e = blockIdx.x * blockDim.x + threadIdx.x;
  if (e < E) atomicAdd(&deg[dst[e]], 1);
}

__global__ void k_scan(const int* __restrict__ deg, int* __restrict__ row_start, int n)
{
  __shared__ int sm[1024];
  __shared__ int run_s;
  if (threadIdx.x == 0) run_s = 0;
  __syncthreads();
  for (int base = 0; base < n; base += 1024) {
    int i = base + (int)threadIdx.x;
    int v = (i < n) ? deg[i] : 0;
    sm[threadIdx.x] = v;
    __syncthreads();
    for (int off = 1; off < 1024; off <<= 1) {
      int y = (threadIdx.x >= (unsigned)off) ? sm[threadIdx.x - off] : 0;
      __syncthreads();
      sm[threadIdx.x] += y;
      __syncthreads();
    }
    int incl = sm[threadIdx.x];
    int run = run_s;
    if (i < n) row_start[i] = run + incl - v;
    __syncthreads();
    if (threadIdx.x == 1023) run_s = run + sm[1023];
    __syncthreads();
  }
  if (threadIdx.x == 0) row_start[n] = run_s;
}

__global__ void k_fill(const int* __restrict__ dst, int* __restrict__ cursor,
                       int* __restrict__ eidx, int E)
{
  int e = blockIdx.x * blockDim.x + threadIdx.x;
  if (e < E) {
    int p = atomicAdd(&cursor[dst[e]], 1);
    eidx[p] = e;
  }
}

// ---------------- aggregation + epilogue -------------------------------------
// mode 0: elu(agg + bias)
// mode 1: elu(agg + hin + bias)   (identity residual; hout may alias hin)
// mode 2: agg + res2 + bias       (linear residual, no act)
__global__ void k_agg(const int* __restrict__ row_start, const int* __restrict__ eidx,
                      const int* __restrict__ src,
                      const float* __restrict__ exv, const float* __restrict__ s,
                      const bf16* __restrict__ ft, const bf16* __restrict__ hin,
                      const bf16* __restrict__ res2, const bf16* __restrict__ bias,
                      bf16* __restrict__ hout,
                      void* __restrict__ dout, long dout_off,
                      const int* __restrict__ flags,
                      int N, int H, int D, int mode)
{
  int t = blockIdx.x * blockDim.x + threadIdx.x;
  int w = t >> 6, lane = t & 63;
  if (w >= N * H || lane >= D) return;
  int n = w / H, h = w % H;
  float sv = s[n * H + h];
  float inv = 1.f / (sv + 1e-16f);
  int st = row_start[n], en = row_start[n + 1];
  float acc = 0.f;
  for (int i = st; i < en; ++i) {
    int e = eidx[i];
    float ex = exv[e * H + h];
    int sn = src[e];
    acc += ex * b2f(ft[(long)sn * H * D + (long)h * D + lane]);
  }
  float r = acc * inv + b2f(bias[h * D + lane]);
  long oi = (long)n * H * D + (long)h * D + lane;
  if (mode == 1) r += b2f(hin[oi]);
  if (mode == 2) r += b2f(res2[(long)n * D + lane]);
  if (mode != 2) r = r > 0.f ? r : expm1f(r);
  if (hout) hout[oi] = f2b(r);
  if (dout) storeOut(dout, dout_off + oi, r, flags[0]);
}

// -----------------------------------------------------------------------------
extern "C" void kernel_launch(void* const* d_in, const int* in_sizes, int n_in,
                              void* d_out, int out_size, void* d_ws, size_t ws_size,
                              hipStream_t stream)
{
  // raw inputs (dtype resolved on device)
  const void* x0    = d_in[0];
  const void* x1    = d_in[1];
  const int*  srcR  = (const int*)d_in[2];
  const int*  dstR  = (const int*)d_in[3];

  // workspace carve-up (~134 MB)
  char* p = (char*)d_ws;
  auto alloc = [&](size_t bytes) { char* r = p; p += (bytes + 255) & ~(size_t)255; return r; };
  int*      flags     = (int*)     alloc(256);
  bf16*     wc        = (bf16*)    alloc((size_t)347312 * 2);
  int*      src32     = (int*)     alloc((size_t)NEDGES * 4);
  int*      dst32     = (int*)     alloc((size_t)NEDGES * 4);
  bf16*     h0        = (bf16*)    alloc((size_t)NNODES * 64 * 2);
  bf16*     hB        = (bf16*)    alloc((size_t)NNODES * 512 * 2);
  bf16*     ft        = (bf16*)    alloc((size_t)NNODES * 512 * 2);
  float*    exv       = (float*)   alloc((size_t)NEDGES * 8 * 4);
  float*    el        = (float*)   alloc((size_t)NNODES * 8 * 4);
  float*    er        = (float*)   alloc((size_t)NNODES * 8 * 4);
  unsigned* m         = (unsigned*)alloc((size_t)NNODES * 8 * 4);
  float*    s         = (float*)   alloc((size_t)NNODES * 8 * 4);
  int*      deg       = (int*)     alloc((size_t)NNODES * 4);
  int*      row_start = (int*)     alloc((size_t)(NNODES + 1) * 4);
  int*      cursor    = (int*)     alloc((size_t)NNODES * 4);
  int*      eidx      = (int*)     alloc((size_t)NEDGES * 4);
  bf16*     res2      = (bf16*)    alloc((size_t)NNODES * 16 * 2);

  const int B = 256;
  auto blk = [](long total, int b) { return (unsigned)((total + b - 1) / b); };

  // ---- detect dtypes, convert indices, canonicalize weights ----
  k_detect<<<1, 256, 0, stream>>>((const unsigned short*)x0, (const unsigned*)dstR, flags);
  k_conv_idx<<<blk(NEDGES, B), B, 0, stream>>>(srcR, dstR, src32, dst32, flags);

  WSrc wsrc;
  const int widx[17] = {4,5,6,7, 8,9,10,11, 12,13,14,15, 16,17,18,19, 20};
  const int wn[17]   = {16384,64,16384,64, 32768,512,512,512, 262144,512,512,512,
                        8192,16,16,16, 8192};
  int wtotal = 0;
  for (int i = 0; i < 17; ++i) { wsrc.p[i] = d_in[widx[i]]; wsrc.n[i] = wn[i]; wtotal += wn[i]; }
  k_canon<<<blk(wtotal, B), B, 0, stream>>>(wsrc, wc, flags, wtotal);

  // canonical weight pointers (same cumulative order)
  long woff[18]; woff[0] = 0;
  for (int i = 0; i < 17; ++i) woff[i + 1] = woff[i] + wn[i];
  const bf16 *fc0W = wc + woff[0],  *fc0b = wc + woff[1];
  const bf16 *fc1W = wc + woff[2],  *fc1b = wc + woff[3];
  const bf16 *W0   = wc + woff[4],  *al0  = wc + woff[5],  *ar0 = wc + woff[6],  *b0 = wc + woff[7];
  const bf16 *W1   = wc + woff[8],  *al1  = wc + woff[9],  *ar1 = wc + woff[10], *b1 = wc + woff[11];
  const bf16 *W2   = wc + woff[12], *al2  = wc + woff[13], *ar2 = wc + woff[14], *b2 = wc + woff[15];
  const bf16 *resW2= wc + woff[16];

  // ---- input projection: h0 ----
  k_fc<<<blk((long)NNODES * 64, B), B, 0, stream>>>(x0, x1, fc0W, fc0b, fc1W, fc1b, h0, flags);

  // ---- CSR build (shared by all 3 layers) ----
  hipMemsetAsync(deg, 0, (size_t)NNODES * 4, stream);
  k_deg<<<blk(NEDGES, B), B, 0, stream>>>(dst32, deg, NEDGES);
  k_scan<<<1, 1024, 0, stream>>>(deg, row_start, NNODES);
  hipMemcpyAsync(cursor, row_start, (size_t)NNODES * 4, hipMemcpyDeviceToDevice, stream);
  k_fill<<<blk(NEDGES, B), B, 0, stream>>>(dst32, cursor, eidx, NEDGES);

  // ---- generic GAT layer ----
  auto gat_layer = [&](const bf16* hin, int K, const bf16* W, const bf16* al,
                       const bf16* ar, const bf16* bias, int H, int D, int mode,
                       const bf16* resbuf, bf16* hout, long dout_off, bool to_dout) {
    int M = H * D;
    k_gemm<<<blk((long)NNODES * M, B), B, 0, stream>>>(hin, W, ft, NNODES, K, M);
    k_elr<<<blk((long)NNODES * H, B), B, 0, stream>>>(ft, al, ar, el, er, NNODES, H, D);
    hipMemsetAsync(m, 0, (size_t)NNODES * H * 4, stream);
    hipMemsetAsync(s, 0, (size_t)NNODES * H * 4, stream);
    k_edge_a<<<blk((long)NEDGES * H, B), B, 0, stream>>>(src32, dst32, el, er, exv, m, NEDGES, H);
    k_edge_b<<<blk((long)NEDGES * H, B), B, 0, stream>>>(dst32, exv, m, s, NEDGES, H);
    k_agg<<<blk((long)NNODES * H * 64, B), B, 0, stream>>>(
        row_start, eidx, src32, exv, s, ft, hin, resbuf, bias,
        hout, to_dout ? d_out : nullptr, dout_off, flags, NNODES, H, D, mode);
  };

  // layer 0: 64 -> 8x64, ELU                    h0 -> hB
  gat_layer(h0, 64, W0, al0, ar0, b0, 8, 64, 0, nullptr, hB, 0, false);

  // layer 1: 512 -> 8x64, identity res, ELU     hB -> hB (in-place) + encoded
  gat_layer(hB, 512, W1, al1, ar1, b1, 8, 64, 1, nullptr, hB, (long)NNODES * 16, true);

  // output layer: 512 -> 1x16, linear res       hB -> logits
  k_gemm<<<blk((long)NNODES * 16, B), B, 0, stream>>>(hB, resW2, res2, NNODES, 512, 16);
  gat_layer(hB, 512, W2, al2, ar2, b2, 1, 16, 2, res2, nullptr, 0, true);
}

// Round 3
// 1725.249 us; speedup vs baseline: 3.3843x; 3.3843x over previous
//
#include <hip/hip_runtime.h>
#include <hip/hip_bf16.h>
#include <math.h>

typedef __hip_bfloat16 bf16;
typedef __attribute__((ext_vector_type(8))) short short8;
typedef __attribute__((ext_vector_type(4))) float floatx4;

#define NNODES 50000
#define NHALF  25000
#define NEDGES 400000
#define NEG_SLOPE 0.2f

__device__ __forceinline__ float b2f(bf16 x){ return __bfloat162float(x); }
__device__ __forceinline__ bf16  f2b(float x){ return __float2bfloat16(x); }

__device__ __forceinline__ unsigned fmap(float x){
  unsigned u = __float_as_uint(x);
  return (u & 0x80000000u) ? ~u : (u | 0x80000000u);
}
__device__ __forceinline__ float funmap(unsigned u){
  unsigned b = (u & 0x80000000u) ? (u & 0x7FFFFFFFu) : ~u;
  return __uint_as_float(b);
}

__device__ __forceinline__ float loadF(const void* p, long i, int f32){
  return f32 ? ((const float*)p)[i] : b2f(((const bf16*)p)[i]);
}
__device__ __forceinline__ void storeOut(void* p, long i, float v, int f32){
  if (f32) ((float*)p)[i] = v; else ((bf16*)p)[i] = f2b(v);
}

// async global->LDS, 16B per lane; lds base must be wave-uniform
__device__ __forceinline__ void gl_lds16(const bf16* g, short* l){
  __builtin_amdgcn_global_load_lds(
      (const __attribute__((address_space(1))) unsigned int*)g,
      (__attribute__((address_space(3))) unsigned int*)l, 16, 0, 0);
}

// ---------------- dtype / index-width detection ------------------------------
__global__ void k_detect(const unsigned short* __restrict__ x0u,
                         const unsigned* __restrict__ dstu,
                         int* __restrict__ flags)
{
  __shared__ int sh_insane;
  __shared__ unsigned sh_or;
  if (threadIdx.x == 0) { sh_insane = 0; sh_or = 0u; }
  __syncthreads();
  int insane = 0; unsigned orv = 0u;
  for (int i = threadIdx.x; i < 2048; i += 256) {
    unsigned short w = x0u[2 * i];
    int ex = (w >> 7) & 0xFF;
    if (w != 0 && (ex < 108 || ex > 142)) insane++;
    orv |= dstu[2 * i + 1];
  }
  atomicAdd(&sh_insane, insane);
  atomicOr(&sh_or, orv);
  __syncthreads();
  if (threadIdx.x == 0) {
    flags[0] = (sh_insane > 512) ? 1 : 0;   // fp32 tensors
    flags[1] = (sh_or == 0u) ? 1 : 0;       // int64 indices
  }
}

__global__ void k_conv_idx(const int* __restrict__ sraw, const int* __restrict__ draw,
                           int* __restrict__ s32, int* __restrict__ d32,
                           const int* __restrict__ flags)
{
  int e = blockIdx.x * blockDim.x + threadIdx.x;
  if (e >= NEDGES) return;
  int stride = flags[1] ? 2 : 1;
  s32[e] = sraw[(long)e * stride];
  d32[e] = draw[(long)e * stride];
}

// ---------------- weight canonicalization to bf16 ----------------------------
struct WSrc { const void* p[17]; int n[17]; };

__global__ void k_canon(WSrc w, bf16* __restrict__ out, const int* __restrict__ flags,
                        int total)
{
  int f32 = flags[0];
  for (int t = blockIdx.x * blockDim.x + threadIdx.x; t < total;
       t += gridDim.x * blockDim.x) {
    int idx = t, k = 0;
    while (idx >= w.n[k]) { idx -= w.n[k]; k++; }
    out[t] = f2b(loadF(w.p[k], idx, f32));
  }
}

// ---------------- x -> contiguous bf16 [50000,256] ---------------------------
__global__ void k_convx(const void* __restrict__ x0, const void* __restrict__ x1,
                        bf16* __restrict__ xb, const int* __restrict__ flags)
{
  long t = (long)blockIdx.x * blockDim.x + threadIdx.x;
  if (t >= (long)NNODES * 256) return;
  int f32 = flags[0];
  long half = (long)NHALF * 256;
  float v = (t < half) ? loadF(x0, t, f32) : loadF(x1, t - half, f32);
  xb[t] = f2b(v);
}

// ---------------- weight transpose: Wt[m][k] = W[k][m], zero-pad m>=M --------
__global__ void k_wt(const bf16* __restrict__ W, bf16* __restrict__ Wt,
                     int K, int M, int Mpad)
{
  int t = blockIdx.x * blockDim.x + threadIdx.x;
  if (t >= Mpad * K) return;
  int m = t / K, k = t % K;
  Wt[t] = (m < M) ? W[(long)k * M + m] : f2b(0.f);
}

// ---------------- MFMA GEMM: C[N,ldc] = A[N,K] @ Wt[Mtiles*128,K]^T ----------
// 128x128 tile, BK=32, 4 waves (2x2), 4x4 16x16x32 frags per wave
__global__ __launch_bounds__(256) void k_gemm_mfma(
    const bf16* __restrict__ A, const bf16* __restrict__ Wt,
    bf16* __restrict__ C, int N, int K, int ldc, int Mout,
    const bf16* __restrict__ bias)
{
  __shared__ __align__(16) short lsA[128 * 32];
  __shared__ __align__(16) short lsB[128 * 32];
  int tid = threadIdx.x;
  int wave = tid >> 6, lane = tid & 63;
  int wm = wave >> 1, wn = wave & 1;
  int rowBase = blockIdx.x * 128;
  int colBase = blockIdx.y * 128;

  floatx4 acc[4][4] = {};
  int laneRow = lane >> 2;          // 0..15 within 16-row chunk
  int laneCol = (lane & 3) * 8;     // element col within BK=32
  int cA0 = wave * 2, cA1 = cA0 + 1;

  for (int kb = 0; kb < K; kb += 32) {
    int r0 = rowBase + cA0 * 16 + laneRow; if (r0 > N - 1) r0 = N - 1;
    int r1 = rowBase + cA1 * 16 + laneRow; if (r1 > N - 1) r1 = N - 1;
    gl_lds16(A + (size_t)r0 * K + kb + laneCol, &lsA[cA0 * 512]);
    gl_lds16(A + (size_t)r1 * K + kb + laneCol, &lsA[cA1 * 512]);
    int m0 = colBase + cA0 * 16 + laneRow;
    int m1 = colBase + cA1 * 16 + laneRow;
    gl_lds16(Wt + (size_t)m0 * K + kb + laneCol, &lsB[cA0 * 512]);
    gl_lds16(Wt + (size_t)m1 * K + kb + laneCol, &lsB[cA1 * 512]);
    __syncthreads();

    short8 af[4], bfr[4];
    int lr = lane & 15, q8 = (lane >> 4) * 8;
    #pragma unroll
    for (int mt = 0; mt < 4; ++mt)
      af[mt] = *(const short8*)&lsA[(wm * 64 + mt * 16 + lr) * 32 + q8];
    #pragma unroll
    for (int nt = 0; nt < 4; ++nt)
      bfr[nt] = *(const short8*)&lsB[(wn * 64 + nt * 16 + lr) * 32 + q8];
    #pragma unroll
    for (int mt = 0; mt < 4; ++mt)
      #pragma unroll
      for (int nt = 0; nt < 4; ++nt)
        acc[mt][nt] = __builtin_amdgcn_mfma_f32_16x16x32_bf16(
            af[mt], bfr[nt], acc[mt][nt], 0, 0, 0);
    __syncthreads();
  }

  int lc = lane & 15, rq = (lane >> 4) * 4;
  #pragma unroll
  for (int mt = 0; mt < 4; ++mt) {
    #pragma unroll
    for (int nt = 0; nt < 4; ++nt) {
      int col = colBase + wn * 64 + nt * 16 + lc;
      if (col >= Mout) continue;
      float bsv = bias ? b2f(bias[col]) : 0.f;
      #pragma unroll
      for (int r = 0; r < 4; ++r) {
        int row = rowBase + wm * 64 + mt * 16 + rq + r;
        if (row < N) C[(size_t)row * ldc + col] = f2b(acc[mt][nt][r] + bsv);
      }
    }
  }
}

// ---------------- attention logits per node ----------------------------------
__global__ void k_elr(const bf16* __restrict__ ft, int ldft,
                      const bf16* __restrict__ al, const bf16* __restrict__ ar,
                      float* __restrict__ el, float* __restrict__ er,
                      int N, int H, int D)
{
  int t = blockIdx.x * blockDim.x + threadIdx.x;
  if (t >= N * H) return;
  int n = t / H, h = t % H;
  const bf16* f = ft + (long)n * ldft + (long)h * D;
  float a = 0.f, b = 0.f;
  for (int d = 0; d < D; ++d) {
    float v = b2f(f[d]);
    a += v * b2f(al[h * D + d]);
    b += v * b2f(ar[h * D + d]);
  }
  el[t] = a; er[t] = b;
}

// ---------------- edge passes ------------------------------------------------
__global__ void k_edge_a(const int* __restrict__ src, const int* __restrict__ dst,
                         const float* __restrict__ el, const float* __restrict__ er,
                         float* __restrict__ eval, unsigned* __restrict__ m,
                         int E, int H)
{
  int t = blockIdx.x * blockDim.x + threadIdx.x;
  if (t >= E * H) return;
  int e = t / H, h = t % H;
  float v = el[src[e] * H + h] + er[dst[e] * H + h];
  v = v > 0.f ? v : NEG_SLOPE * v;
  eval[t] = v;
  atomicMax(&m[dst[e] * H + h], fmap(v));
}

__global__ void k_edge_b(const int* __restrict__ dst,
                         float* __restrict__ eval, const unsigned* __restrict__ m,
                         float* __restrict__ s, int E, int H)
{
  int t = blockIdx.x * blockDim.x + threadIdx.x;
  if (t >= E * H) return;
  int e = t / H, h = t % H;
  float mm = funmap(m[dst[e] * H + h]);
  float ex = expf(eval[t] - mm);
  eval[t] = ex;
  atomicAdd(&s[dst[e] * H + h], ex);
}

// ---------------- CSR build --------------------------------------------------
__global__ void k_deg(const int* __restrict__ dst, int* __restrict__ deg, int E)
{
  int e = blockIdx.x * blockDim.x + threadIdx.x;
  if (e < E) atomicAdd(&deg[dst[e]], 1);
}

__global__ void k_scan(const int* __restrict__ deg, int* __restrict__ row_start, int n)
{
  __shared__ int sm[1024];
  __shared__ int run_s;
  if (threadIdx.x == 0) run_s = 0;
  __syncthreads();
  for (int base = 0; base < n; base += 1024) {
    int i = base + (int)threadIdx.x;
    int v = (i < n) ? deg[i] : 0;
    sm[threadIdx.x] = v;
    __syncthreads();
    for (int off = 1; off < 1024; off <<= 1) {
      int y = (threadIdx.x >= (unsigned)off) ? sm[threadIdx.x - off] : 0;
      __syncthreads();
      sm[threadIdx.x] += y;
      __syncthreads();
    }
    int incl = sm[threadIdx.x];
    int run = run_s;
    if (i < n) row_start[i] = run + incl - v;
    __syncthreads();
    if (threadIdx.x == 1023) run_s = run + sm[1023];
    __syncthreads();
  }
  if (threadIdx.x == 0) row_start[n] = run_s;
}

__global__ void k_fill(const int* __restrict__ dst, int* __restrict__ cursor,
                       int* __restrict__ eidx, int E)
{
  int e = blockIdx.x * blockDim.x + threadIdx.x;
  if (e < E) {
    int p = atomicAdd(&cursor[dst[e]], 1);
    eidx[p] = e;
  }
}

// ---------------- aggregation + epilogue -------------------------------------
__global__ void k_agg(const int* __restrict__ row_start, const int* __restrict__ eidx,
                      const int* __restrict__ src,
                      const float* __restrict__ exv, const float* __restrict__ s,
                      const bf16* __restrict__ ft, int ldft,
                      const bf16* __restrict__ hin,
                      const bf16* __restrict__ res2, int ldres,
                      const bf16* __restrict__ bias,
                      bf16* __restrict__ hout,
                      void* __restrict__ dout, long dout_off,
                      const int* __restrict__ flags,
                      int N, int H, int D, int mode)
{
  int t = blockIdx.x * blockDim.x + threadIdx.x;
  int w = t >> 6, lane = t & 63;
  if (w >= N * H || lane >= D) return;
  int n = w / H, h = w % H;
  float sv = s[n * H + h];
  float inv = 1.f / (sv + 1e-16f);
  int st = row_start[n], en = row_start[n + 1];
  float acc = 0.f;
  for (int i = st; i < en; ++i) {
    int e = eidx[i];
    float ex = exv[e * H + h];
    int sn = src[e];
    acc += ex * b2f(ft[(long)sn * ldft + (long)h * D + lane]);
  }
  float r = acc * inv + b2f(bias[h * D + lane]);
  long oi = (long)n * H * D + (long)h * D + lane;
  if (mode == 1) r += b2f(hin[oi]);
  if (mode == 2) r += b2f(res2[(long)n * ldres + lane]);
  if (mode != 2) r = r > 0.f ? r : expm1f(r);
  if (hout) hout[oi] = f2b(r);
  if (dout) storeOut(dout, dout_off + oi, r, flags[0]);
}

// -----------------------------------------------------------------------------
extern "C" void kernel_launch(void* const* d_in, const int* in_sizes, int n_in,
                              void* d_out, int out_size, void* d_ws, size_t ws_size,
                              hipStream_t stream)
{
  const void* x0   = d_in[0];
  const void* x1   = d_in[1];
  const int*  srcR = (const int*)d_in[2];
  const int*  dstR = (const int*)d_in[3];

  char* p = (char*)d_ws;
  auto alloc = [&](size_t bytes) { char* r = p; p += (bytes + 255) & ~(size_t)255; return r; };
  int*      flags     = (int*)     alloc(256);
  bf16*     wc        = (bf16*)    alloc((size_t)347312 * 2);
  int*      src32     = (int*)     alloc((size_t)NEDGES * 4);
  int*      dst32     = (int*)     alloc((size_t)NEDGES * 4);
  bf16*     xb        = (bf16*)    alloc((size_t)NNODES * 256 * 2);
  bf16*     h0        = (bf16*)    alloc((size_t)NNODES * 64 * 2);
  bf16*     hB        = (bf16*)    alloc((size_t)NNODES * 512 * 2);
  bf16*     ft        = (bf16*)    alloc((size_t)NNODES * 512 * 2);
  bf16*     ft2       = (bf16*)    alloc((size_t)NNODES * 32 * 2);
  float*    exv       = (float*)   alloc((size_t)NEDGES * 8 * 4);
  float*    el        = (float*)   alloc((size_t)NNODES * 8 * 4);
  float*    er        = (float*)   alloc((size_t)NNODES * 8 * 4);
  unsigned* m         = (unsigned*)alloc((size_t)NNODES * 8 * 4);
  float*    s         = (float*)   alloc((size_t)NNODES * 8 * 4);
  int*      deg       = (int*)     alloc((size_t)NNODES * 4);
  int*      row_start = (int*)     alloc((size_t)(NNODES + 1) * 4);
  int*      cursor    = (int*)     alloc((size_t)NNODES * 4);
  int*      eidx      = (int*)     alloc((size_t)NEDGES * 4);
  bf16*     fc0t      = (bf16*)    alloc((size_t)128 * 256 * 2);
  bf16*     fc1t      = (bf16*)    alloc((size_t)128 * 256 * 2);
  bf16*     W0t       = (bf16*)    alloc((size_t)512 * 64 * 2);
  bf16*     W1t       = (bf16*)    alloc((size_t)512 * 512 * 2);
  bf16*     W2c       = (bf16*)    alloc((size_t)128 * 512 * 2);

  const int B = 256;
  auto blk = [](long total, int b) { return (unsigned)((total + b - 1) / b); };

  // ---- detect dtypes, convert indices, canonicalize weights + x ----
  k_detect<<<1, 256, 0, stream>>>((const unsigned short*)x0, (const unsigned*)dstR, flags);
  k_conv_idx<<<blk(NEDGES, B), B, 0, stream>>>(srcR, dstR, src32, dst32, flags);

  WSrc wsrc;
  const int widx[17] = {4,5,6,7, 8,9,10,11, 12,13,14,15, 16,17,18,19, 20};
  const int wn[17]   = {16384,64,16384,64, 32768,512,512,512, 262144,512,512,512,
                        8192,16,16,16, 8192};
  int wtotal = 0;
  for (int i = 0; i < 17; ++i) { wsrc.p[i] = d_in[widx[i]]; wsrc.n[i] = wn[i]; wtotal += wn[i]; }
  k_canon<<<blk(wtotal, B), B, 0, stream>>>(wsrc, wc, flags, wtotal);
  k_convx<<<blk((long)NNODES * 256, B), B, 0, stream>>>(x0, x1, xb, flags);

  long woff[18]; woff[0] = 0;
  for (int i = 0; i < 17; ++i) woff[i + 1] = woff[i] + wn[i];
  const bf16 *fc0W = wc + woff[0],  *fc0b = wc + woff[1];
  const bf16 *fc1W = wc + woff[2],  *fc1b = wc + woff[3];
  const bf16 *W0   = wc + woff[4],  *al0  = wc + woff[5],  *ar0 = wc + woff[6],  *b0 = wc + woff[7];
  const bf16 *W1   = wc + woff[8],  *al1  = wc + woff[9],  *ar1 = wc + woff[10], *b1 = wc + woff[11];
  const bf16 *W2   = wc + woff[12], *al2  = wc + woff[13], *ar2 = wc + woff[14], *b2 = wc + woff[15];
  const bf16 *resW2= wc + woff[16];

  // ---- weight transposes (B^T form, zero-padded to 128-row multiples) ----
  k_wt<<<blk(128 * 256, B), B, 0, stream>>>(fc0W, fc0t, 256, 64, 128);
  k_wt<<<blk(128 * 256, B), B, 0, stream>>>(fc1W, fc1t, 256, 64, 128);
  k_wt<<<blk(512 * 64, B), B, 0, stream>>>(W0, W0t, 64, 512, 512);
  k_wt<<<blk(512 * 512, B), B, 0, stream>>>(W1, W1t, 512, 512, 512);
  k_wt<<<blk(128 * 512, B), B, 0, stream>>>(W2, W2c, 512, 16, 128);        // rows 0..15 + zero pad
  k_wt<<<blk(16 * 512, B), B, 0, stream>>>(resW2, W2c + 16 * 512, 512, 16, 16); // rows 16..31

  // ---- CSR build ----
  hipMemsetAsync(deg, 0, (size_t)NNODES * 4, stream);
  k_deg<<<blk(NEDGES, B), B, 0, stream>>>(dst32, deg, NEDGES);
  k_scan<<<1, 1024, 0, stream>>>(deg, row_start, NNODES);
  hipMemcpyAsync(cursor, row_start, (size_t)NNODES * 4, hipMemcpyDeviceToDevice, stream);
  k_fill<<<blk(NEDGES, B), B, 0, stream>>>(dst32, cursor, eidx, NEDGES);

  auto gemm = [&](const bf16* A, const bf16* Wt, bf16* C, int N, int K,
                  int ldc, int Mout, int ytiles, const bf16* bias) {
    dim3 g(blk(N, 128), ytiles);
    k_gemm_mfma<<<g, 256, 0, stream>>>(A, Wt, C, N, K, ldc, Mout, bias);
  };

  // ---- input projections (MFMA) ----
  gemm(xb, fc0t, h0, NHALF, 256, 64, 64, 1, fc0b);
  gemm(xb + (size_t)NHALF * 256, fc1t, h0 + (size_t)NHALF * 64, NHALF, 256, 64, 64, 1, fc1b);

  auto attn = [&](const bf16* ftp, int ldft, const bf16* al, const bf16* ar,
                  const bf16* bias, int H, int D, int mode, const bf16* hin,
                  const bf16* resb, int ldres, bf16* hout, long dout_off, bool to_dout) {
    k_elr<<<blk((long)NNODES * H, B), B, 0, stream>>>(ftp, ldft, al, ar, el, er, NNODES, H, D);
    hipMemsetAsync(m, 0, (size_t)NNODES * H * 4, stream);
    hipMemsetAsync(s, 0, (size_t)NNODES * H * 4, stream);
    k_edge_a<<<blk((long)NEDGES * H, B), B, 0, stream>>>(src32, dst32, el, er, exv, m, NEDGES, H);
    k_edge_b<<<blk((long)NEDGES * H, B), B, 0, stream>>>(dst32, exv, m, s, NEDGES, H);
    k_agg<<<blk((long)NNODES * H * 64, B), B, 0, stream>>>(
        row_start, eidx, src32, exv, s, ftp, ldft, hin, resb, ldres, bias,
        hout, to_dout ? d_out : nullptr, dout_off, flags, NNODES, H, D, mode);
  };

  // layer 0: 64 -> 8x64, ELU
  gemm(h0, W0t, ft, NNODES, 64, 512, 512, 4, nullptr);
  attn(ft, 512, al0, ar0, b0, 8, 64, 0, nullptr, nullptr, 0, hB, 0, false);

  // layer 1: 512 -> 8x64, identity residual, ELU (+ encoded output)
  gemm(hB, W1t, ft, NNODES, 512, 512, 512, 4, nullptr);
  attn(ft, 512, al1, ar1, b1, 8, 64, 1, hB, nullptr, 0, hB, (long)NNODES * 16, true);

  // output layer: 512 -> 1x16 (+ fused resW2 projection in cols 16..31)
  gemm(hB, W2c, ft2, NNODES, 512, 32, 32, 1, nullptr);
  attn(ft2, 32, al2, ar2, b2, 1, 16, 2, nullptr, ft2 + 16, 32, nullptr, 0, true);
}

// Round 4
// 811.391 us; speedup vs baseline: 7.1960x; 2.1263x over previous
//
#include <hip/hip_runtime.h>
#include <hip/hip_bf16.h>
#include <math.h>

typedef __hip_bfloat16 bf16;
typedef __attribute__((ext_vector_type(8))) short short8;
typedef __attribute__((ext_vector_type(8))) unsigned short ushort8;
typedef __attribute__((ext_vector_type(4))) float floatx4;

#define NNODES 50000
#define NHALF  25000
#define NEDGES 400000
#define NEG_SLOPE 0.2f

__device__ __forceinline__ float b2f(bf16 x){ return __bfloat162float(x); }
__device__ __forceinline__ bf16  f2b(float x){ return __float2bfloat16(x); }
__device__ __forceinline__ float u2f(unsigned short u){ return __uint_as_float(((unsigned)u) << 16); }

__device__ __forceinline__ float loadF(const void* p, long i, int f32){
  return f32 ? ((const float*)p)[i] : b2f(((const bf16*)p)[i]);
}
__device__ __forceinline__ void storeOut(void* p, long i, float v, int f32){
  if (f32) ((float*)p)[i] = v; else ((bf16*)p)[i] = f2b(v);
}

// async global->LDS, 16B per lane; lds base must be wave-uniform
__device__ __forceinline__ void gl_lds16(const bf16* g, short* l){
  __builtin_amdgcn_global_load_lds(
      (const __attribute__((address_space(1))) unsigned int*)g,
      (__attribute__((address_space(3))) unsigned int*)l, 16, 0, 0);
}

// ---------------- dtype / index-width detection ------------------------------
__global__ void k_detect(const unsigned short* __restrict__ x0u,
                         const unsigned* __restrict__ dstu,
                         int* __restrict__ flags)
{
  __shared__ int sh_insane;
  __shared__ unsigned sh_or;
  if (threadIdx.x == 0) { sh_insane = 0; sh_or = 0u; }
  __syncthreads();
  int insane = 0; unsigned orv = 0u;
  for (int i = threadIdx.x; i < 2048; i += 256) {
    unsigned short w = x0u[2 * i];
    int ex = (w >> 7) & 0xFF;
    if (w != 0 && (ex < 108 || ex > 142)) insane++;
    orv |= dstu[2 * i + 1];
  }
  atomicAdd(&sh_insane, insane);
  atomicOr(&sh_or, orv);
  __syncthreads();
  if (threadIdx.x == 0) {
    flags[0] = (sh_insane > 512) ? 1 : 0;   // fp32 tensors
    flags[1] = (sh_or == 0u) ? 1 : 0;       // int64 indices
  }
}

__global__ void k_conv_idx(const int* __restrict__ sraw, const int* __restrict__ draw,
                           int* __restrict__ s32, int* __restrict__ d32,
                           const int* __restrict__ flags)
{
  int e = blockIdx.x * blockDim.x + threadIdx.x;
  if (e >= NEDGES) return;
  int stride = flags[1] ? 2 : 1;
  s32[e] = sraw[(long)e * stride];
  d32[e] = draw[(long)e * stride];
}

// ---------------- weight canonicalization to bf16 ----------------------------
struct WSrc { const void* p[17]; int n[17]; };

__global__ void k_canon(WSrc w, bf16* __restrict__ out, const int* __restrict__ flags,
                        int total)
{
  int f32 = flags[0];
  for (int t = blockIdx.x * blockDim.x + threadIdx.x; t < total;
       t += gridDim.x * blockDim.x) {
    int idx = t, k = 0;
    while (idx >= w.n[k]) { idx -= w.n[k]; k++; }
    out[t] = f2b(loadF(w.p[k], idx, f32));
  }
}

// ---------------- x -> contiguous bf16 [50000,256] ---------------------------
__global__ void k_convx(const void* __restrict__ x0, const void* __restrict__ x1,
                        bf16* __restrict__ xb, const int* __restrict__ flags)
{
  long t = (long)blockIdx.x * blockDim.x + threadIdx.x;
  if (t >= (long)NNODES * 256) return;
  int f32 = flags[0];
  long half = (long)NHALF * 256;
  float v = (t < half) ? loadF(x0, t, f32) : loadF(x1, t - half, f32);
  xb[t] = f2b(v);
}

// ---------------- weight transpose: Wt[m][k] = W[k][m], zero-pad m>=M --------
__global__ void k_wt(const bf16* __restrict__ W, bf16* __restrict__ Wt,
                     int K, int M, int Mpad)
{
  int t = blockIdx.x * blockDim.x + threadIdx.x;
  if (t >= Mpad * K) return;
  int m = t / K, k = t % K;
  Wt[t] = (m < M) ? W[(long)k * M + m] : f2b(0.f);
}

// ---------------- MFMA GEMM: C[N,ldc] = A[N,K] @ Wt^T ------------------------
__global__ __launch_bounds__(256) void k_gemm_mfma(
    const bf16* __restrict__ A, const bf16* __restrict__ Wt,
    bf16* __restrict__ C, int N, int K, int ldc, int Mout,
    const bf16* __restrict__ bias)
{
  __shared__ __align__(16) short lsA[128 * 32];
  __shared__ __align__(16) short lsB[128 * 32];
  int tid = threadIdx.x;
  int wave = tid >> 6, lane = tid & 63;
  int wm = wave >> 1, wn = wave & 1;
  int rowBase = blockIdx.x * 128;
  int colBase = blockIdx.y * 128;

  floatx4 acc[4][4] = {};
  int laneRow = lane >> 2;
  int laneCol = (lane & 3) * 8;
  int cA0 = wave * 2, cA1 = cA0 + 1;

  for (int kb = 0; kb < K; kb += 32) {
    int r0 = rowBase + cA0 * 16 + laneRow; if (r0 > N - 1) r0 = N - 1;
    int r1 = rowBase + cA1 * 16 + laneRow; if (r1 > N - 1) r1 = N - 1;
    gl_lds16(A + (size_t)r0 * K + kb + laneCol, &lsA[cA0 * 512]);
    gl_lds16(A + (size_t)r1 * K + kb + laneCol, &lsA[cA1 * 512]);
    int m0 = colBase + cA0 * 16 + laneRow;
    int m1 = colBase + cA1 * 16 + laneRow;
    gl_lds16(Wt + (size_t)m0 * K + kb + laneCol, &lsB[cA0 * 512]);
    gl_lds16(Wt + (size_t)m1 * K + kb + laneCol, &lsB[cA1 * 512]);
    __syncthreads();

    short8 af[4], bfr[4];
    int lr = lane & 15, q8 = (lane >> 4) * 8;
    #pragma unroll
    for (int mt = 0; mt < 4; ++mt)
      af[mt] = *(const short8*)&lsA[(wm * 64 + mt * 16 + lr) * 32 + q8];
    #pragma unroll
    for (int nt = 0; nt < 4; ++nt)
      bfr[nt] = *(const short8*)&lsB[(wn * 64 + nt * 16 + lr) * 32 + q8];
    #pragma unroll
    for (int mt = 0; mt < 4; ++mt)
      #pragma unroll
      for (int nt = 0; nt < 4; ++nt)
        acc[mt][nt] = __builtin_amdgcn_mfma_f32_16x16x32_bf16(
            af[mt], bfr[nt], acc[mt][nt], 0, 0, 0);
    __syncthreads();
  }

  int lc = lane & 15, rq = (lane >> 4) * 4;
  #pragma unroll
  for (int mt = 0; mt < 4; ++mt) {
    #pragma unroll
    for (int nt = 0; nt < 4; ++nt) {
      int col = colBase + wn * 64 + nt * 16 + lc;
      if (col >= Mout) continue;
      float bsv = bias ? b2f(bias[col]) : 0.f;
      #pragma unroll
      for (int r = 0; r < 4; ++r) {
        int row = rowBase + wm * 64 + mt * 16 + rq + r;
        if (row < N) C[(size_t)row * ldc + col] = f2b(acc[mt][nt][r] + bsv);
      }
    }
  }
}

// ---------------- attention logits (H=8, D=64, ft [N,512]) -------------------
__global__ __launch_bounds__(256) void k_elr8(
    const bf16* __restrict__ ft,
    const bf16* __restrict__ al, const bf16* __restrict__ ar,
    float* __restrict__ el, float* __restrict__ er)
{
  __shared__ float sal[512], sar[512];
  for (int i = threadIdx.x; i < 512; i += 256) { sal[i] = b2f(al[i]); sar[i] = b2f(ar[i]); }
  __syncthreads();
  int t = blockIdx.x * blockDim.x + threadIdx.x;
  if (t >= NNODES * 8) return;
  int n = t >> 3, h = t & 7;
  const unsigned short* f = (const unsigned short*)ft + (size_t)n * 512 + h * 64;
  float a = 0.f, b = 0.f;
  #pragma unroll
  for (int j = 0; j < 8; ++j) {
    ushort8 v = *(const ushort8*)&f[j * 8];
    #pragma unroll
    for (int k = 0; k < 8; ++k) {
      float x = u2f(v[k]);
      a += x * sal[h * 64 + j * 8 + k];
      b += x * sar[h * 64 + j * 8 + k];
    }
  }
  el[t] = a; er[t] = b;
}

// ---------------- attention logits (H=1, D=16, ft2 [N,32]) -------------------
__global__ void k_elr1(const bf16* __restrict__ ft2,
                       const bf16* __restrict__ al, const bf16* __restrict__ ar,
                       float* __restrict__ el, float* __restrict__ er)
{
  int n = blockIdx.x * blockDim.x + threadIdx.x;
  if (n >= NNODES) return;
  const unsigned short* f = (const unsigned short*)ft2 + (size_t)n * 32;
  float a = 0.f, b = 0.f;
  #pragma unroll
  for (int d = 0; d < 16; ++d) {
    float x = u2f(f[d]);
    a += x * b2f(al[d]);
    b += x * b2f(ar[d]);
  }
  el[n] = a; er[n] = b;
}

// ---------------- CSR build --------------------------------------------------
__global__ void k_deg(const int* __restrict__ dst, int* __restrict__ deg, int E)
{
  int e = blockIdx.x * blockDim.x + threadIdx.x;
  if (e < E) atomicAdd(&deg[dst[e]], 1);
}

__global__ void k_scan(const int* __restrict__ deg, int* __restrict__ row_start, int n)
{
  __shared__ int sm[1024];
  __shared__ int run_s;
  if (threadIdx.x == 0) run_s = 0;
  __syncthreads();
  for (int base = 0; base < n; base += 1024) {
    int i = base + (int)threadIdx.x;
    int v = (i < n) ? deg[i] : 0;
    sm[threadIdx.x] = v;
    __syncthreads();
    for (int off = 1; off < 1024; off <<= 1) {
      int y = (threadIdx.x >= (unsigned)off) ? sm[threadIdx.x - off] : 0;
      __syncthreads();
      sm[threadIdx.x] += y;
      __syncthreads();
    }
    int incl = sm[threadIdx.x];
    int run = run_s;
    if (i < n) row_start[i] = run + incl - v;
    __syncthreads();
    if (threadIdx.x == 1023) run_s = run + sm[1023];
    __syncthreads();
  }
  if (threadIdx.x == 0) row_start[n] = run_s;
}

__global__ void k_fill(const int* __restrict__ src, const int* __restrict__ dst,
                       int* __restrict__ cursor, int* __restrict__ csr_src, int E)
{
  int e = blockIdx.x * blockDim.x + threadIdx.x;
  if (e < E) {
    int p = atomicAdd(&cursor[dst[e]], 1);
    csr_src[p] = src[e];
  }
}

// ---------------- fused softmax + aggregation, H=8 D=64 ----------------------
// one wave per node; lane owns dims [lane*8, lane*8+8); head group g = lane>>3
// mode 0: elu(agg + bias)      mode 1: elu(agg + hin + bias), hout may alias hin
__global__ __launch_bounds__(256) void k_agg8(
    const int* __restrict__ row_start, const int* __restrict__ csr_src,
    const float* __restrict__ el, const float* __restrict__ er,
    const bf16* __restrict__ ft, const bf16* __restrict__ hin,
    const bf16* __restrict__ bias,
    bf16* __restrict__ hout, void* __restrict__ dout, long dout_off,
    const int* __restrict__ flags, int mode)
{
  int wv = (int)((blockIdx.x * blockDim.x + threadIdx.x) >> 6);
  int lane = threadIdx.x & 63;
  if (wv >= NNODES) return;
  int n = wv, g = lane >> 3;
  int st = row_start[n], en = row_start[n + 1];
  float ern = er[n * 8 + g];

  // pass 1: per-head max over incoming edges
  float mx = -1e30f;
  for (int i = st; i < en; ++i) {
    int sn = csr_src[i];
    float v = el[sn * 8 + g] + ern;
    v = v > 0.f ? v : NEG_SLOPE * v;
    mx = fmaxf(mx, v);
  }

  // pass 2: exp-weighted row gather
  float ssum = 0.f;
  float acc[8] = {};
  const unsigned short* ftS = (const unsigned short*)ft;
  for (int i = st; i < en; ++i) {
    int sn = csr_src[i];
    float v = el[sn * 8 + g] + ern;
    v = v > 0.f ? v : NEG_SLOPE * v;
    float ex = expf(v - mx);
    ssum += ex;
    ushort8 row = *(const ushort8*)&ftS[(size_t)sn * 512 + lane * 8];
    #pragma unroll
    for (int j = 0; j < 8; ++j)
      acc[j] += ex * u2f(row[j]);
  }

  float inv = 1.f / (ssum + 1e-16f);
  int f32 = flags[0];
  short8 outv;
  #pragma unroll
  for (int j = 0; j < 8; ++j) {
    int col = lane * 8 + j;
    float r = acc[j] * inv + b2f(bias[col]);
    if (mode == 1) r += b2f(hin[(size_t)n * 512 + col]);
    r = r > 0.f ? r : expm1f(r);
    bf16 o = f2b(r);
    outv[j] = *(short*)&o;
    if (dout) storeOut(dout, dout_off + (size_t)n * 512 + col, r, f32);
  }
  *(short8*)&hout[(size_t)n * 512 + lane * 8] = outv;
}

// ---------------- fused softmax + aggregation, H=1 D=16 (output layer) -------
// ft2 [N,32]: cols 0..15 = W2 proj, cols 16..31 = resW2 proj
__global__ __launch_bounds__(256) void k_agg1(
    const int* __restrict__ row_start, const int* __restrict__ csr_src,
    const float* __restrict__ el, const float* __restrict__ er,
    const bf16* __restrict__ ft2, const bf16* __restrict__ bias,
    void* __restrict__ dout, const int* __restrict__ flags)
{
  int wv = (int)((blockIdx.x * blockDim.x + threadIdx.x) >> 6);
  int lane = threadIdx.x & 63;
  if (wv >= NNODES || lane >= 16) return;
  int n = wv;
  int st = row_start[n], en = row_start[n + 1];
  float ern = er[n];
  float mx = -1e30f;
  for (int i = st; i < en; ++i) {
    int sn = csr_src[i];
    float v = el[sn] + ern;
    v = v > 0.f ? v : NEG_SLOPE * v;
    mx = fmaxf(mx, v);
  }
  float ssum = 0.f, acc = 0.f;
  for (int i = st; i < en; ++i) {
    int sn = csr_src[i];
    float v = el[sn] + ern;
    v = v > 0.f ? v : NEG_SLOPE * v;
    float ex = expf(v - mx);
    ssum += ex;
    acc += ex * b2f(ft2[(size_t)sn * 32 + lane]);
  }
  float r = acc / (ssum + 1e-16f) + b2f(bias[lane]) + b2f(ft2[(size_t)n * 32 + 16 + lane]);
  storeOut(dout, (size_t)n * 16 + lane, r, flags[0]);
}

// -----------------------------------------------------------------------------
extern "C" void kernel_launch(void* const* d_in, const int* in_sizes, int n_in,
                              void* d_out, int out_size, void* d_ws, size_t ws_size,
                              hipStream_t stream)
{
  const void* x0   = d_in[0];
  const void* x1   = d_in[1];
  const int*  srcR = (const int*)d_in[2];
  const int*  dstR = (const int*)d_in[3];

  char* p = (char*)d_ws;
  auto alloc = [&](size_t bytes) { char* r = p; p += (bytes + 255) & ~(size_t)255; return r; };
  int*      flags     = (int*)  alloc(256);
  bf16*     wc        = (bf16*) alloc((size_t)347312 * 2);
  int*      src32     = (int*)  alloc((size_t)NEDGES * 4);
  int*      dst32     = (int*)  alloc((size_t)NEDGES * 4);
  bf16*     xb        = (bf16*) alloc((size_t)NNODES * 256 * 2);
  bf16*     h0        = (bf16*) alloc((size_t)NNODES * 64 * 2);
  bf16*     hB        = (bf16*) alloc((size_t)NNODES * 512 * 2);
  bf16*     ft        = (bf16*) alloc((size_t)NNODES * 512 * 2);
  bf16*     ft2       = (bf16*) alloc((size_t)NNODES * 32 * 2);
  float*    el        = (float*)alloc((size_t)NNODES * 8 * 4);
  float*    er        = (float*)alloc((size_t)NNODES * 8 * 4);
  int*      deg       = (int*)  alloc((size_t)NNODES * 4);
  int*      row_start = (int*)  alloc((size_t)(NNODES + 1) * 4);
  int*      cursor    = (int*)  alloc((size_t)NNODES * 4);
  int*      csr_src   = (int*)  alloc((size_t)NEDGES * 4);
  bf16*     fc0t      = (bf16*) alloc((size_t)128 * 256 * 2);
  bf16*     fc1t      = (bf16*) alloc((size_t)128 * 256 * 2);
  bf16*     W0t       = (bf16*) alloc((size_t)512 * 64 * 2);
  bf16*     W1t       = (bf16*) alloc((size_t)512 * 512 * 2);
  bf16*     W2c       = (bf16*) alloc((size_t)128 * 512 * 2);

  const int B = 256;
  auto blk = [](long total, int b) { return (unsigned)((total + b - 1) / b); };

  // ---- detect dtypes, convert indices, canonicalize weights + x ----
  k_detect<<<1, 256, 0, stream>>>((const unsigned short*)x0, (const unsigned*)dstR, flags);
  k_conv_idx<<<blk(NEDGES, B), B, 0, stream>>>(srcR, dstR, src32, dst32, flags);

  WSrc wsrc;
  const int widx[17] = {4,5,6,7, 8,9,10,11, 12,13,14,15, 16,17,18,19, 20};
  const int wn[17]   = {16384,64,16384,64, 32768,512,512,512, 262144,512,512,512,
                        8192,16,16,16, 8192};
  int wtotal = 0;
  for (int i = 0; i < 17; ++i) { wsrc.p[i] = d_in[widx[i]]; wsrc.n[i] = wn[i]; wtotal += wn[i]; }
  k_canon<<<blk(wtotal, B), B, 0, stream>>>(wsrc, wc, flags, wtotal);
  k_convx<<<blk((long)NNODES * 256, B), B, 0, stream>>>(x0, x1, xb, flags);

  long woff[18]; woff[0] = 0;
  for (int i = 0; i < 17; ++i) woff[i + 1] = woff[i] + wn[i];
  const bf16 *fc0W = wc + woff[0],  *fc0b = wc + woff[1];
  const bf16 *fc1W = wc + woff[2],  *fc1b = wc + woff[3];
  const bf16 *W0   = wc + woff[4],  *al0  = wc + woff[5],  *ar0 = wc + woff[6],  *b0 = wc + woff[7];
  const bf16 *W1   = wc + woff[8],  *al1  = wc + woff[9],  *ar1 = wc + woff[10], *b1 = wc + woff[11];
  const bf16 *W2   = wc + woff[12], *al2  = wc + woff[13], *ar2 = wc + woff[14], *b2 = wc + woff[15];
  const bf16 *resW2= wc + woff[16];

  // ---- weight transposes ----
  k_wt<<<blk(128 * 256, B), B, 0, stream>>>(fc0W, fc0t, 256, 64, 128);
  k_wt<<<blk(128 * 256, B), B, 0, stream>>>(fc1W, fc1t, 256, 64, 128);
  k_wt<<<blk(512 * 64, B), B, 0, stream>>>(W0, W0t, 64, 512, 512);
  k_wt<<<blk(512 * 512, B), B, 0, stream>>>(W1, W1t, 512, 512, 512);
  k_wt<<<blk(128 * 512, B), B, 0, stream>>>(W2, W2c, 512, 16, 128);
  k_wt<<<blk(16 * 512, B), B, 0, stream>>>(resW2, W2c + 16 * 512, 512, 16, 16);

  // ---- CSR build (csr_src holds source node per slot) ----
  hipMemsetAsync(deg, 0, (size_t)NNODES * 4, stream);
  k_deg<<<blk(NEDGES, B), B, 0, stream>>>(dst32, deg, NEDGES);
  k_scan<<<1, 1024, 0, stream>>>(deg, row_start, NNODES);
  hipMemcpyAsync(cursor, row_start, (size_t)NNODES * 4, hipMemcpyDeviceToDevice, stream);
  k_fill<<<blk(NEDGES, B), B, 0, stream>>>(src32, dst32, cursor, csr_src, NEDGES);

  auto gemm = [&](const bf16* A, const bf16* Wt, bf16* C, int N, int K,
                  int ldc, int Mout, int ytiles, const bf16* bias) {
    dim3 g(blk(N, 128), ytiles);
    k_gemm_mfma<<<g, 256, 0, stream>>>(A, Wt, C, N, K, ldc, Mout, bias);
  };

  // ---- input projections ----
  gemm(xb, fc0t, h0, NHALF, 256, 64, 64, 1, fc0b);
  gemm(xb + (size_t)NHALF * 256, fc1t, h0 + (size_t)NHALF * 64, NHALF, 256, 64, 64, 1, fc1b);

  unsigned aggGrid = blk((long)NNODES * 64, B);

  // ---- layer 0: 64 -> 8x64, ELU ----
  gemm(h0, W0t, ft, NNODES, 64, 512, 512, 4, nullptr);
  k_elr8<<<blk((long)NNODES * 8, B), B, 0, stream>>>(ft, al0, ar0, el, er);
  k_agg8<<<aggGrid, B, 0, stream>>>(row_start, csr_src, el, er, ft, nullptr, b0,
                                    hB, nullptr, 0, flags, 0);

  // ---- layer 1: 512 -> 8x64, identity residual, ELU (+ encoded out) ----
  gemm(hB, W1t, ft, NNODES, 512, 512, 512, 4, nullptr);
  k_elr8<<<blk((long)NNODES * 8, B), B, 0, stream>>>(ft, al1, ar1, el, er);
  k_agg8<<<aggGrid, B, 0, stream>>>(row_start, csr_src, el, er, ft, hB, b1,
                                    hB, d_out, (long)NNODES * 16, flags, 1);

  // ---- output layer: 512 -> 1x16 (+ fused resW2 in cols 16..31) ----
  gemm(hB, W2c, ft2, NNODES, 512, 32, 32, 1, nullptr);
  k_elr1<<<blk(NNODES, B), B, 0, stream>>>(ft2, al2, ar2, el, er);
  k_agg1<<<aggGrid, B, 0, stream>>>(row_start, csr_src, el, er, ft2, b2, d_out, flags);
}